// Round 9
// baseline (136.126 us; speedup 1.0000x reference)
//
#include <hip/hip_runtime.h>
#include <hip/hip_fp16.h>

#define N_NODES 50000
#define N_EDGES 800000
#define N_GRAPHS 256
#define D_FEAT 96
#define HIDDEN 32

#define NB 391        // bins: bin = dst >> 7 (128 nodes/bin), 49999>>7 = 390
#define PB 625        // partition blocks
#define PCHUNK 1280   // 625 * 1280 = 800000 exactly
#define EPT 5         // edges per thread (1280 / 256)
#define GWIN 8        // pooled-graph LDS window per 128-node bin
#define LCAP 2560     // per-bin edge cap (mean 2046, sd ~45 -> 11 sigma)
#define L2CAP 3584    // 8-padded node-sorted list cap (2046 + 128*7 max pad)
#define XT 64         // nodes per xw1 tile block
#define XBLK 782      // ceil(50000/64)
#define XS_STRIDE 97  // padded LDS row stride (conflict-free lane=node reads)
#define DUMMY_NODE N_NODES   // extra zeroed y16 row for list padding

// ---------------------------------------------------------------------------
// Kernel A: blocks 0..PB-1: EXACT per-block counting-sort of 1280 edges by
// bin -> ONE coalesced contiguous write (no scattered stores, no overflow).
// Blocks PB..: y16 = fp16(x @ W1) via LDS-staged tiles + init chores.
__global__ void __launch_bounds__(256)
k_front(const float* __restrict__ x, const float* __restrict__ W1,
        __half* __restrict__ y16,
        const int* __restrict__ src, const int* __restrict__ dst,
        unsigned int* __restrict__ binned, unsigned int* __restrict__ co,
        float* __restrict__ sums, float* __restrict__ counts) {
    int blk = blockIdx.x;
    int tid = threadIdx.x;
    if (blk < PB) {
        __shared__ unsigned int sorted[PCHUNK];  // 5 KB
        __shared__ unsigned int sA[512];         // histogram + scan ping
        __shared__ unsigned int sB[512];         // scan pong
        __shared__ unsigned int lcur[NB];

        for (int i = tid; i < 512; i += 256) sA[i] = 0;
        __syncthreads();

        int e0 = blk * PCHUNK;
        unsigned int pay[EPT];
        int bb[EPT];
#pragma unroll
        for (int i = 0; i < EPT; ++i) {          // hold edges in registers
            int e = e0 + i * 256 + tid;
            int s = src[e];
            int d = dst[e];
            int b = d >> 7;
            pay[i] = (unsigned)s | ((unsigned)(d & 127) << 16);
            bb[i] = b;
            atomicAdd(&sA[b], 1u);
        }
        __syncthreads();

        // inclusive scan over 512 (two elems/thread, 9 steps)
        unsigned *ps = sA, *pd = sB;
        for (int d = 1; d < 512; d <<= 1) {
            for (int idx = tid; idx < 512; idx += 256) {
                unsigned v = ps[idx];
                if (idx >= d) v += ps[idx - d];
                pd[idx] = v;
            }
            __syncthreads();
            unsigned* t = ps; ps = pd; pd = t;
        }
        // ps = inclusive scan. excl(i) = i ? ps[i-1] : 0 ; cnt(i) = ps[i]-excl(i)
        for (int i = tid; i < NB; i += 256) {
            unsigned incl = ps[i];
            unsigned excl = i ? ps[i - 1] : 0u;
            lcur[i] = excl;
            co[(size_t)i * PB + blk] = excl | ((incl - excl) << 16);
        }
        __syncthreads();

#pragma unroll
        for (int i = 0; i < EPT; ++i) {
            unsigned pos = atomicAdd(&lcur[bb[i]], 1u);
            sorted[pos] = pay[i];
        }
        __syncthreads();

        // ONE coalesced contiguous stream out (5 KB)
        for (int i = tid; i < PCHUNK; i += 256)
            binned[(size_t)blk * PCHUNK + i] = sorted[i];
    } else {
        __shared__ float xs[XT * XS_STRIDE];     // 24.8 KB
        int xb = blk - PB;
        int n0 = xb * XT;
        int nn = N_NODES - n0; if (nn > XT) nn = XT;

        int gid = xb * 256 + tid;                // init chores (run before k_agg)
        if (gid < N_GRAPHS * HIDDEN) sums[gid] = 0.f;
        if (gid < N_GRAPHS) counts[gid] = 0.f;
        if (xb == 0 && tid < HIDDEN)
            y16[(size_t)DUMMY_NODE * HIDDEN + tid] = __float2half(0.f);

        const float4* xsrc = (const float4*)(x + (size_t)n0 * D_FEAT);
        int nf4 = nn * (D_FEAT / 4);             // up to 1536
        for (int idx = tid; idx < nf4; idx += 256) {
            int ln = (idx * 2731) >> 16;         // idx / 24 for idx < 1536
            int k4 = idx - ln * 24;
            float4 v = xsrc[idx];
            float* dp = &xs[ln * XS_STRIDE + k4 * 4];
            dp[0] = v.x; dp[1] = v.y; dp[2] = v.z; dp[3] = v.w;
        }
        __syncthreads();

        int lane = tid & 63;                     // node within tile
        int f0 = (tid >> 6) << 3;                // wave-uniform feature base
        f0 = __builtin_amdgcn_readfirstlane(f0);

        if (lane < nn) {
            const float* xr = &xs[lane * XS_STRIDE];
            const float4* W1v = (const float4*)W1;
            float acc[8];
#pragma unroll
            for (int j = 0; j < 8; ++j) acc[j] = 0.f;
#pragma unroll
            for (int k = 0; k < D_FEAT; ++k) {
                float xv = xr[k];
                float4 wa = W1v[k * 8 + (f0 >> 2)];
                float4 wb = W1v[k * 8 + (f0 >> 2) + 1];
                acc[0] = fmaf(xv, wa.x, acc[0]);
                acc[1] = fmaf(xv, wa.y, acc[1]);
                acc[2] = fmaf(xv, wa.z, acc[2]);
                acc[3] = fmaf(xv, wa.w, acc[3]);
                acc[4] = fmaf(xv, wb.x, acc[4]);
                acc[5] = fmaf(xv, wb.y, acc[5]);
                acc[6] = fmaf(xv, wb.z, acc[6]);
                acc[7] = fmaf(xv, wb.w, acc[7]);
            }
            __half2 h01 = __floats2half2_rn(acc[0], acc[1]);
            __half2 h23 = __floats2half2_rn(acc[2], acc[3]);
            __half2 h45 = __floats2half2_rn(acc[4], acc[5]);
            __half2 h67 = __floats2half2_rn(acc[6], acc[7]);
            float4 pack;
            pack.x = __uint_as_float(*(const unsigned*)&h01);
            pack.y = __uint_as_float(*(const unsigned*)&h23);
            pack.z = __uint_as_float(*(const unsigned*)&h45);
            pack.w = __uint_as_float(*(const unsigned*)&h67);
            *(float4*)&y16[(size_t)(n0 + lane) * HIDDEN + f0] = pack;
        }
    }
}

// ---------------------------------------------------------------------------
// Kernel B: per-bin (128 nodes): gather runs from compact binned buffer ->
// counting-sort to 8-padded per-node CSR -> pipelined register gather ->
// MLP via shuffles -> windowed mean-pool. 391 blocks x 1024 threads.
__global__ void __launch_bounds__(1024)
k_agg(const unsigned int* __restrict__ binned, const unsigned int* __restrict__ co,
      const __half* __restrict__ y16, const int* __restrict__ batch,
      const float* __restrict__ b1, const float* __restrict__ W2,
      const float* __restrict__ b2,
      float* __restrict__ sums, float* __restrict__ counts) {
    __shared__ unsigned int list[LCAP];        // 10 KB packed (src|dstlo<<16)
    __shared__ unsigned short list2[L2CAP];    // 7 KB node-sorted src (8-padded)
    __shared__ unsigned int sA[1024], sB[1024];// 8 KB scan ping-pong
    __shared__ unsigned int ncnt[128];
    __shared__ unsigned int offs[129];
    __shared__ unsigned int cur[128];
    __shared__ float w2s[HIDDEN * HIDDEN];     // 4 KB
    __shared__ float accs[GWIN * HIDDEN];      // 1 KB
    __shared__ float cntsl[GWIN];

    int tid = threadIdx.x;
    int bin = blockIdx.x;
    if (tid < 128) ncnt[tid] = 0;
    for (int i = tid; i < HIDDEN * HIDDEN; i += 1024) w2s[i] = W2[i];
    if (tid < GWIN * HIDDEN) accs[tid] = 0.f;
    if (tid < GWIN) cntsl[tid] = 0.f;

    // read this bin's 625 run descriptors (coalesced) and scan run counts
    unsigned myofs = 0, mycnt = 0;
    if (tid < PB) {
        unsigned w = co[(size_t)bin * PB + tid];
        myofs = w & 0xFFFFu;
        mycnt = w >> 16;
    }
    sA[tid] = mycnt;
    __syncthreads();

    unsigned *ps = sA, *pd = sB;
    for (int d = 1; d < 1024; d <<= 1) {
        unsigned v = ps[tid];
        if (tid >= d) v += ps[tid - d];
        pd[tid] = v;
        __syncthreads();
        unsigned* t = ps; ps = pd; pd = t;
    }
    int ecount = (int)ps[PB - 1];
    if (ecount > LCAP) ecount = LCAP;
    unsigned mybase = (tid < PB && tid > 0) ? ps[tid - 1] : 0u;
    __syncthreads();

    // pack: each of 625 threads copies its run (avg 3.3 edges) from the
    // COMPACT binned buffer (3.2 MB, L3-resident)
    if (tid < PB) {
        const unsigned int* run = binned + (size_t)tid * PCHUNK + myofs;
        for (unsigned i = 0; i < mycnt; ++i) {
            unsigned pos = mybase + i;
            if (pos < LCAP) list[pos] = run[i];
        }
    }
    __syncthreads();

    // per-node histogram (128 nodes)
    for (int e = tid; e < ecount; e += 1024)
        atomicAdd(&ncnt[list[e] >> 16], 1u);
    __syncthreads();

    // exclusive scan over 8-PADDED node counts (128 entries, 7 steps)
    if (tid < 128) sA[tid] = (ncnt[tid] + 7u) & ~7u;
    __syncthreads();
    ps = sA; pd = sB;
    for (int d = 1; d < 128; d <<= 1) {
        if (tid < 128) { unsigned v = ps[tid]; if (tid >= d) v += ps[tid - d]; pd[tid] = v; }
        __syncthreads();
        unsigned* t = ps; ps = pd; pd = t;
    }
    if (tid < 128) {
        offs[tid + 1] = ps[tid];
        cur[tid] = tid ? ps[tid - 1] : 0u;
    }
    if (tid == 0) offs[0] = 0;
    __syncthreads();

    // place src ids into 8-padded node-sorted list2
    for (int e = tid; e < ecount; e += 1024) {
        unsigned p = list[e];
        unsigned pos = atomicAdd(&cur[p >> 16], 1u);
        if (pos < L2CAP) list2[pos] = (unsigned short)(p & 0xFFFFu);
    }
    __syncthreads();
    if (tid < 128) {                              // pad with dummy (zero) row
        unsigned i0 = cur[tid], i1 = offs[tid + 1];
        for (unsigned i = i0; i < i1 && i < L2CAP; ++i)
            list2[i] = (unsigned short)DUMMY_NODE;
    }
    __syncthreads();

    int node0 = bin << 7;
    int nn = N_NODES - node0; if (nn > 128) nn = 128;
    int g = tid >> 5;      // group 0..31 (two per wave64)
    int f = tid & 31;      // feature lane
    int gfirst = batch[node0];

    for (int ln = g * 4; ln < g * 4 + 4; ++ln) {
        if (ln >= nn) break;
        int node = node0 + ln;
        float acc = __half2float(y16[(size_t)node * HIDDEN + f]);   // self term
        int j = offs[ln], jend = offs[ln + 1];                      // both %8 == 0
        for (; j < jend; j += 8) {                 // pure 8-deep pipeline
            ushort4 qa = *(const ushort4*)&list2[j];
            ushort4 qb = *(const ushort4*)&list2[j + 4];
            float a0 = __half2float(y16[(size_t)qa.x * HIDDEN + f]);
            float a1 = __half2float(y16[(size_t)qa.y * HIDDEN + f]);
            float a2 = __half2float(y16[(size_t)qa.z * HIDDEN + f]);
            float a3 = __half2float(y16[(size_t)qa.w * HIDDEN + f]);
            float a4 = __half2float(y16[(size_t)qb.x * HIDDEN + f]);
            float a5 = __half2float(y16[(size_t)qb.y * HIDDEN + f]);
            float a6 = __half2float(y16[(size_t)qb.z * HIDDEN + f]);
            float a7 = __half2float(y16[(size_t)qb.w * HIDDEN + f]);
            acc += ((a0 + a1) + (a2 + a3)) + ((a4 + a5) + (a6 + a7));
        }

        float h1 = fmaxf(acc + b1[f], 0.f);
        float h2 = b2[f];
#pragma unroll
        for (int k = 0; k < HIDDEN; ++k)           // h1[k] via intra-group shuffle
            h2 = fmaf(__shfl(h1, k, 32), w2s[k * HIDDEN + f], h2);
        float h = fmaxf(h2, 0.f);

        int gr = batch[node];
        int b = gr - gfirst;
        if (b < GWIN) {
            atomicAdd(&accs[b * HIDDEN + f], h);
            if (f == 0) atomicAdd(&cntsl[b], 1.f);
        } else {
            atomicAdd(&sums[(size_t)gr * HIDDEN + f], h);
            if (f == 0) atomicAdd(&counts[gr], 1.f);
        }
    }
    __syncthreads();

    for (int i = tid; i < GWIN * HIDDEN; i += 1024) {
        float v = accs[i];
        if (v != 0.f) atomicAdd(&sums[(size_t)gfirst * HIDDEN + i], v);
    }
    if (tid < GWIN) {
        float c = cntsl[tid];
        if (c != 0.f) atomicAdd(&counts[gfirst + tid], c);
    }
}

// ---------------------------------------------------------------------------
// Kernel C: out[g] = (sums[g]/max(counts[g],1)) @ Wc + bc
__global__ void k_out(const float* __restrict__ sums, const float* __restrict__ counts,
                      const float* __restrict__ Wc, const float* __restrict__ bc,
                      float* __restrict__ out) {
    int g = threadIdx.x;
    if (g >= N_GRAPHS) return;
    float inv = 1.f / fmaxf(counts[g], 1.f);
    float o0 = bc[0], o1 = bc[1];
#pragma unroll
    for (int k = 0; k < HIDDEN; ++k) {
        float p = sums[(size_t)g * HIDDEN + k] * inv;
        o0 = fmaf(p, Wc[k * 2 + 0], o0);
        o1 = fmaf(p, Wc[k * 2 + 1], o1);
    }
    out[g * 2 + 0] = o0;
    out[g * 2 + 1] = o1;
}

// ---------------------------------------------------------------------------
extern "C" void kernel_launch(void* const* d_in, const int* in_sizes, int n_in,
                              void* d_out, int out_size, void* d_ws, size_t ws_size,
                              hipStream_t stream) {
    const float* x     = (const float*)d_in[0];
    const int*   ei    = (const int*)d_in[1];   // [2, N_EDGES]: src row then dst row
    const int*   batch = (const int*)d_in[2];
    const float* W1    = (const float*)d_in[3];
    const float* b1    = (const float*)d_in[4];
    const float* W2    = (const float*)d_in[5];
    const float* b2    = (const float*)d_in[6];
    const float* Wc    = (const float*)d_in[7];
    const float* bc    = (const float*)d_in[8];
    float* out = (float*)d_out;

    // Workspace layout (byte offsets):
    //   0         sums    8192 f             (32768 B)
    //   32768     counts  256 f              (1024 B)
    //   33792     co      NB*PB u32          (977500 B, pad to 1011456)
    //   1011456   binned  N_EDGES u32        (3200000 B, compact)
    //   4211456   y16     (N_NODES+1)*32 h   (3200064 B)   total ~7.4 MB
    char* ws = (char*)d_ws;
    float*        sums   = (float*)ws;
    float*        counts = (float*)(ws + 32768);
    unsigned int* co     = (unsigned int*)(ws + 33792);
    unsigned int* binned = (unsigned int*)(ws + 1011456);
    __half*       y16    = (__half*)(ws + 4211456);

    k_front<<<PB + XBLK, 256, 0, stream>>>(
        x, W1, y16, ei, ei + N_EDGES, binned, co, sums, counts);

    k_agg<<<NB, 1024, 0, stream>>>(binned, co, y16, batch,
                                   b1, W2, b2, sums, counts);

    k_out<<<1, 256, 0, stream>>>(sums, counts, Wc, bc, out);
}